// Round 1
// baseline (1314.620 us; speedup 1.0000x reference)
//
#include <hip/hip_runtime.h>
#include <hip/hip_bf16.h>

// Fused 2-layer tanh-RNN + FC + sigmoid, one persistent block per batch row.
// B=256 blocks x 256 threads (4 waves). Weights live in VGPRs as bf16 MFMA
// fragments (wave w owns output cols [64w,64w+64)). Per step: only h-vector
// redistribution goes through LDS; one __syncthreads per step.

#define BB  256
#define SS  512
#define DIN 64
#define HH  256

typedef __attribute__((ext_vector_type(8))) short short8;
typedef __attribute__((ext_vector_type(4))) float f32x4;

#define MFMA(a, b, c) __builtin_amdgcn_mfma_f32_16x16x32_bf16((a), (b), (c), 0, 0, 0)

__device__ __forceinline__ short bf16r(float f) {
    union { float f; unsigned u; } v; v.f = f;
    unsigned r = v.u + 0x7FFFu + ((v.u >> 16) & 1u);   // RTNE
    return (short)(r >> 16);
}

__device__ __forceinline__ short8 ldfrag(const float* __restrict__ p) {
    f32x4 a = *(const f32x4*)p;
    f32x4 b = *(const f32x4*)(p + 4);
    short8 v;
#pragma unroll
    for (int j = 0; j < 4; ++j) { v[j] = bf16r(a[j]); v[4 + j] = bf16r(b[j]); }
    return v;
}

__global__ __launch_bounds__(256, 1)
void rnn_fused_kernel(const float* __restrict__ x,
                      const float* __restrict__ Wih0, const float* __restrict__ Whh0,
                      const float* __restrict__ bih0, const float* __restrict__ bhh0,
                      const float* __restrict__ Wih1, const float* __restrict__ Whh1,
                      const float* __restrict__ bih1, const float* __restrict__ bhh1,
                      const float* __restrict__ Wfc,  const float* __restrict__ bfc,
                      float* __restrict__ out)
{
    const int b    = blockIdx.x;
    const int tid  = threadIdx.x;
    const int wid  = tid >> 6;       // wave 0..3
    const int lane = tid & 63;
    const int c15  = lane & 15;      // col within 16x16 tile
    const int kg   = lane >> 4;      // k-group 0..3

    __shared__ alignas(16) ushort h0b[2][HH];   // bf16 h0, double-buffered
    __shared__ alignas(16) ushort h1b[2][HH];   // bf16 h1
    __shared__ alignas(16) ushort xbuf[2][DIN]; // bf16 x_t
    __shared__ float h1f[HH];                   // f32 final h1 for FC

    // stage x(t=0); zero h(-1)
    if (tid < DIN) xbuf[0][tid] = (ushort)bf16r(x[(size_t)b * SS * DIN + tid]);
    if (tid < HH)  { h0b[1][tid] = 0; h1b[1][tid] = 0; }

    // ---- weight fragments (bf16, register-resident) ----
    // B-operand frag for tile n, k-frag kf: lane holds W[col][32kf + 8kg + j],
    // col = 64*wid + 16*n + (lane&15).
    short8 wih0[2][4], whh0[8][4], wih1[8][4], whh1[8][4];
    float  bias0[4], bias1[4];
#pragma unroll
    for (int n = 0; n < 4; ++n) {
        const int col = 64 * wid + 16 * n + c15;
        bias0[n] = bih0[col] + bhh0[col];
        bias1[n] = bih1[col] + bhh1[col];
#pragma unroll
        for (int kf = 0; kf < 2; ++kf)
            wih0[kf][n] = ldfrag(Wih0 + col * DIN + 32 * kf + kg * 8);
#pragma unroll
        for (int kf = 0; kf < 8; ++kf) {
            whh0[kf][n] = ldfrag(Whh0 + col * HH + 32 * kf + kg * 8);
            wih1[kf][n] = ldfrag(Wih1 + col * HH + 32 * kf + kg * 8);
            whh1[kf][n] = ldfrag(Whh1 + col * HH + 32 * kf + kg * 8);
        }
    }
    __syncthreads();

    const f32x4 vzero = {0.f, 0.f, 0.f, 0.f};
    f32x4 acc[4];
    float h1v[4] = {0.f, 0.f, 0.f, 0.f};

    for (int t = 0; t < SS; ++t) {
        const int cur = t & 1, prv = (t + 1) & 1;

        // A-frags of x_t (all 16 rows identical -> M=1 use)
        short8 ax0 = *(const short8*)(&xbuf[cur][kg * 8]);
        short8 ax1 = *(const short8*)(&xbuf[cur][32 + kg * 8]);

        // issue-early load of x(t+1) (wave 0), write-late below (T14)
        float xnext = 0.f;
        const bool do_stage = (t + 1 < SS) && (tid < DIN);
        if (do_stage)
            xnext = x[(size_t)b * SS * DIN + (size_t)(t + 1) * DIN + tid];

        // ---- layer 0: pre0 = x_t @ Wih0^T + h0(t-1) @ Whh0^T + b ----
#pragma unroll
        for (int n = 0; n < 4; ++n) acc[n] = vzero;
#pragma unroll
        for (int n = 0; n < 4; ++n) acc[n] = MFMA(ax0, wih0[0][n], acc[n]);
#pragma unroll
        for (int n = 0; n < 4; ++n) acc[n] = MFMA(ax1, wih0[1][n], acc[n]);
#pragma unroll
        for (int kf = 0; kf < 8; ++kf) {
            short8 a = *(const short8*)(&h0b[prv][32 * kf + kg * 8]);
#pragma unroll
            for (int n = 0; n < 4; ++n) acc[n] = MFMA(a, whh0[kf][n], acc[n]);
        }
        float h0v[4];
#pragma unroll
        for (int n = 0; n < 4; ++n) h0v[n] = tanhf(acc[n][0] + bias0[n]);
        if (lane < 16) {
#pragma unroll
            for (int n = 0; n < 4; ++n)
                h0b[cur][64 * wid + 16 * n + lane] = (ushort)bf16r(h0v[n]);
        }
        if (do_stage) xbuf[prv][tid] = (ushort)bf16r(xnext);
        __syncthreads();   // the single per-step barrier

        // ---- layer 1: pre1 = h0(t) @ Wih1^T + h1(t-1) @ Whh1^T + b ----
#pragma unroll
        for (int n = 0; n < 4; ++n) acc[n] = vzero;
#pragma unroll
        for (int kf = 0; kf < 8; ++kf) {
            short8 a = *(const short8*)(&h0b[cur][32 * kf + kg * 8]);
#pragma unroll
            for (int n = 0; n < 4; ++n) acc[n] = MFMA(a, wih1[kf][n], acc[n]);
        }
#pragma unroll
        for (int kf = 0; kf < 8; ++kf) {
            short8 a = *(const short8*)(&h1b[prv][32 * kf + kg * 8]);
#pragma unroll
            for (int n = 0; n < 4; ++n) acc[n] = MFMA(a, whh1[kf][n], acc[n]);
        }
#pragma unroll
        for (int n = 0; n < 4; ++n) h1v[n] = tanhf(acc[n][0] + bias1[n]);
        if (lane < 16) {
#pragma unroll
            for (int n = 0; n < 4; ++n)
                h1b[cur][64 * wid + 16 * n + lane] = (ushort)bf16r(h1v[n]);
        }
        // no trailing barrier needed: next consumers are separated by the
        // next iteration's mid-step barrier (hazard analysis in notes)
    }

    // ---- FC + sigmoid on final h1 (kept in f32) ----
    if (lane < 16) {
#pragma unroll
        for (int n = 0; n < 4; ++n) h1f[64 * wid + 16 * n + lane] = h1v[n];
    }
    __syncthreads();
    if (wid == 0) {
        float p = h1f[4 * lane + 0] * Wfc[4 * lane + 0]
                + h1f[4 * lane + 1] * Wfc[4 * lane + 1]
                + h1f[4 * lane + 2] * Wfc[4 * lane + 2]
                + h1f[4 * lane + 3] * Wfc[4 * lane + 3];
#pragma unroll
        for (int off = 32; off > 0; off >>= 1) p += __shfl_down(p, off);
        if (lane == 0) {
            float z = p + bfc[0];
            out[b] = 1.f / (1.f + expf(-z));
        }
    }
}

extern "C" void kernel_launch(void* const* d_in, const int* in_sizes, int n_in,
                              void* d_out, int out_size, void* d_ws, size_t ws_size,
                              hipStream_t stream) {
    (void)in_sizes; (void)n_in; (void)d_ws; (void)ws_size; (void)out_size;
    const float* x    = (const float*)d_in[0];
    const float* Wih0 = (const float*)d_in[1];
    const float* Whh0 = (const float*)d_in[2];
    const float* bih0 = (const float*)d_in[3];
    const float* bhh0 = (const float*)d_in[4];
    const float* Wih1 = (const float*)d_in[5];
    const float* Whh1 = (const float*)d_in[6];
    const float* bih1 = (const float*)d_in[7];
    const float* bhh1 = (const float*)d_in[8];
    const float* Wfc  = (const float*)d_in[9];
    const float* bfc  = (const float*)d_in[10];
    float* out = (float*)d_out;

    rnn_fused_kernel<<<dim3(BB), dim3(256), 0, stream>>>(
        x, Wih0, Whh0, bih0, bhh0, Wih1, Whh1, bih1, bhh1, Wfc, bfc, out);
}

// Round 2
// 893.376 us; speedup vs baseline: 1.4715x; 1.4715x over previous
//
#include <hip/hip_runtime.h>
#include <hip/hip_bf16.h>

// Fused 2-layer tanh-RNN + FC + sigmoid. One block per batch row, 4 waves.
// Round-2 changes vs round-1:
//  * Wih1/Whh1 fragments live in AGPRs via inline-asm MFMA "a" constraint
//    (round-1 spilled: 416 regs needed > 256 arch VGPRs -> 58MB scratch).
//  * x-projection (xp) and layer-1 input projection (u = Wih1 h0) computed
//    per 16-step chunk with M=16 MFMAs (batched, full M use).
//  * Layer-0 recurrence of chunk c interleaved with layer-1 recurrence of
//    chunk c-1: 8 independent MFMA chains, one barrier per combined step.

#define BB  256
#define SS  512
#define DIN 64
#define HH  256
#define TT  16
#define NC  (SS/TT)

typedef __attribute__((ext_vector_type(8))) short short8;
typedef __attribute__((ext_vector_type(4))) float f32x4;

#define MFMA(a, b, c) __builtin_amdgcn_mfma_f32_16x16x32_bf16((a), (b), (c), 0, 0, 0)

// MFMA with B operand pinned to AGPRs (register allocator moves the
// loop-invariant weight fragment into the accumulator file).
__device__ __forceinline__ void mfma_agpr(f32x4& acc, short8 a, short8 b) {
    asm("v_mfma_f32_16x16x32_bf16 %0, %1, %2, %0" : "+v"(acc) : "v"(a), "a"(b));
}

__device__ __forceinline__ short bf16r(float f) {
    union { float f; unsigned u; } v; v.f = f;
    unsigned r = v.u + 0x7FFFu + ((v.u >> 16) & 1u);   // RTNE
    return (short)(r >> 16);
}

__device__ __forceinline__ float bf2f(ushort h) {
    union { unsigned u; float f; } v; v.u = ((unsigned)h) << 16;
    return v.f;
}

__device__ __forceinline__ short8 ldfrag(const float* __restrict__ p) {
    f32x4 a = *(const f32x4*)p;
    f32x4 b = *(const f32x4*)(p + 4);
    short8 v;
#pragma unroll
    for (int j = 0; j < 4; ++j) { v[j] = bf16r(a[j]); v[4 + j] = bf16r(b[j]); }
    return v;
}

// tanh(x) = 1 - 2/(exp2(x*2/ln2)+1); exact at +-inf, ~1ulp core ops.
__device__ __forceinline__ float tanh_fast(float x) {
    float e = __builtin_amdgcn_exp2f(x * 2.885390081777927f);
    return 1.0f - 2.0f * __builtin_amdgcn_rcpf(e + 1.0f);
}

__global__ __launch_bounds__(256, 1)
void rnn_fused_kernel(const float* __restrict__ x,
                      const float* __restrict__ Wih0, const float* __restrict__ Whh0,
                      const float* __restrict__ bih0, const float* __restrict__ bhh0,
                      const float* __restrict__ Wih1, const float* __restrict__ Whh1,
                      const float* __restrict__ bih1, const float* __restrict__ bhh1,
                      const float* __restrict__ Wfc,  const float* __restrict__ bfc,
                      float* __restrict__ out)
{
    const int b    = blockIdx.x;
    const int tid  = threadIdx.x;
    const int wid  = tid >> 6;
    const int lane = tid & 63;
    const int c15  = lane & 15;
    const int kg   = lane >> 4;
    const int cbase = 64 * wid + c15;

    __shared__ alignas(16) ushort xchunk[TT][DIN];      // bf16 x chunk      (2 KB)
    __shared__ alignas(16) float  xp[TT][HH];           // f32 xp(+bias0)   (16 KB)
    __shared__ alignas(16) ushort h0hist[TT + 1][HH];   // bf16 h0, slot0=carry (8.5 KB)
    __shared__ alignas(16) float  uch[TT][HH];          // f32 u(+bias1)    (16 KB)
    __shared__ alignas(16) ushort h1pp[2][HH];          // bf16 h1 ping-pong (1 KB)
    __shared__ alignas(16) short8 wih0lds[2][4][256];   // staged Wih0 frags (32 KB)

    // zero carry-in states
    h0hist[0][tid] = 0;
    h1pp[1][tid]   = 0;

    // ---- weight fragments ----
    // B-frag for output col = cbase+16n, k = 32kf + 8kg + j.
    float  bias0[4], bias1[4];
    short8 whh0v[8][4];             // VGPR-resident
    short8 wih1a[8][4], whh1a[8][4];// AGPR-resident (via mfma_agpr)
#pragma unroll
    for (int n = 0; n < 4; ++n) {
        const int col = cbase + 16 * n;
        bias0[n] = bih0[col] + bhh0[col];
        bias1[n] = bih1[col] + bhh1[col];
#pragma unroll
        for (int kf = 0; kf < 2; ++kf)
            wih0lds[kf][n][tid] = ldfrag(Wih0 + (size_t)col * DIN + 32 * kf + kg * 8);
#pragma unroll
        for (int kf = 0; kf < 8; ++kf) {
            whh0v[kf][n] = ldfrag(Whh0 + (size_t)col * HH + 32 * kf + kg * 8);
            wih1a[kf][n] = ldfrag(Wih1 + (size_t)col * HH + 32 * kf + kg * 8);
            whh1a[kf][n] = ldfrag(Whh1 + (size_t)col * HH + 32 * kf + kg * 8);
        }
    }

    const f32x4 vz = {0.f, 0.f, 0.f, 0.f};
    const float* xb = x + (size_t)b * SS * DIN;
    float xr[4];
#pragma unroll
    for (int i = 0; i < 4; ++i) xr[i] = xb[tid + 256 * i];

    for (int c = 0; c < NC; ++c) {
        // ---- phase A: stage x chunk, compute xp = x @ Wih0^T + bias0 ----
#pragma unroll
        for (int i = 0; i < 4; ++i) {
            const int idx = tid + 256 * i;
            xchunk[idx >> 6][idx & 63] = (ushort)bf16r(xr[i]);
        }
        if (c + 1 < NC) {                       // prefetch next chunk's x
            const float* xs = xb + (size_t)(c + 1) * TT * DIN;
#pragma unroll
            for (int i = 0; i < 4; ++i) xr[i] = xs[tid + 256 * i];
        }
        __syncthreads();
        {
            f32x4 axp[4] = {vz, vz, vz, vz};
#pragma unroll
            for (int kf = 0; kf < 2; ++kf) {
                const short8 ax = *(const short8*)(&xchunk[c15][32 * kf + 8 * kg]);
#pragma unroll
                for (int n = 0; n < 4; ++n) axp[n] = MFMA(ax, wih0lds[kf][n][tid], axp[n]);
            }
#pragma unroll
            for (int n = 0; n < 4; ++n)
#pragma unroll
                for (int j = 0; j < 4; ++j)
                    xp[4 * kg + j][cbase + 16 * n] = axp[n][j] + bias0[n];
        }
        __syncthreads();

        // ---- phase B(c) interleaved with D(c-1): the two recurrences ----
        for (int r = 0; r < TT; ++r) {
            const bool doD = (c > 0);
            const int dcur = r & 1, dprv = dcur ^ 1;  // layer-1 ping-pong parity
            float xpv[4], uv[4] = {0.f, 0.f, 0.f, 0.f};
#pragma unroll
            for (int n = 0; n < 4; ++n) xpv[n] = xp[r][cbase + 16 * n];
            if (doD) {
#pragma unroll
                for (int n = 0; n < 4; ++n) uv[n] = uch[r][cbase + 16 * n];
            }
            f32x4 a0[4] = {vz, vz, vz, vz}, a1[4] = {vz, vz, vz, vz};
#pragma unroll
            for (int kf = 0; kf < 8; ++kf) {
                const short8 ah0 = *(const short8*)(&h0hist[r][32 * kf + 8 * kg]);
#pragma unroll
                for (int n = 0; n < 4; ++n) a0[n] = MFMA(ah0, whh0v[kf][n], a0[n]);
                if (doD) {
                    const short8 ah1 = *(const short8*)(&h1pp[dprv][32 * kf + 8 * kg]);
#pragma unroll
                    for (int n = 0; n < 4; ++n) mfma_agpr(a1[n], ah1, whh1a[kf][n]);
                }
            }
            if (lane < 16) {
#pragma unroll
                for (int n = 0; n < 4; ++n)
                    h0hist[r + 1][cbase + 16 * n] = (ushort)bf16r(tanh_fast(a0[n][0] + xpv[n]));
                if (doD) {
#pragma unroll
                    for (int n = 0; n < 4; ++n)
                        h1pp[dcur][cbase + 16 * n] = (ushort)bf16r(tanh_fast(a1[n][0] + uv[n]));
                }
            }
            __syncthreads();
        }

        // ---- phase C: u(c) = h0hist @ Wih1^T + bias1 (batched, M=16) ----
        {
            f32x4 au[4] = {vz, vz, vz, vz};
#pragma unroll
            for (int kf = 0; kf < 8; ++kf) {
                const short8 a = *(const short8*)(&h0hist[1 + c15][32 * kf + 8 * kg]);
#pragma unroll
                for (int n = 0; n < 4; ++n) mfma_agpr(au[n], a, wih1a[kf][n]);
            }
#pragma unroll
            for (int n = 0; n < 4; ++n)
#pragma unroll
                for (int j = 0; j < 4; ++j)
                    uch[4 * kg + j][cbase + 16 * n] = au[n][j] + bias1[n];
            h0hist[0][tid] = h0hist[16][tid];   // carry h0 into next chunk
        }
        __syncthreads();
    }

    // ---- drain: D steps for the last chunk ----
    for (int r = 0; r < TT; ++r) {
        const int dcur = r & 1, dprv = dcur ^ 1;
        float uv[4];
#pragma unroll
        for (int n = 0; n < 4; ++n) uv[n] = uch[r][cbase + 16 * n];
        f32x4 a1[4] = {vz, vz, vz, vz};
#pragma unroll
        for (int kf = 0; kf < 8; ++kf) {
            const short8 ah1 = *(const short8*)(&h1pp[dprv][32 * kf + 8 * kg]);
#pragma unroll
            for (int n = 0; n < 4; ++n) mfma_agpr(a1[n], ah1, whh1a[kf][n]);
        }
        if (lane < 16) {
#pragma unroll
            for (int n = 0; n < 4; ++n)
                h1pp[dcur][cbase + 16 * n] = (ushort)bf16r(tanh_fast(a1[n][0] + uv[n]));
        }
        __syncthreads();
    }

    // ---- FC + sigmoid on final h1 (t=511 -> parity 1) ----
    if (wid == 0) {
        float p = 0.f;
#pragma unroll
        for (int i = 0; i < 4; ++i)
            p += bf2f(h1pp[1][4 * lane + i]) * Wfc[4 * lane + i];
#pragma unroll
        for (int off = 32; off > 0; off >>= 1) p += __shfl_down(p, off);
        if (lane == 0) {
            const float z = p + bfc[0];
            out[b] = 1.f / (1.f + expf(-z));
        }
    }
}

extern "C" void kernel_launch(void* const* d_in, const int* in_sizes, int n_in,
                              void* d_out, int out_size, void* d_ws, size_t ws_size,
                              hipStream_t stream) {
    (void)in_sizes; (void)n_in; (void)d_ws; (void)ws_size; (void)out_size;
    const float* x    = (const float*)d_in[0];
    const float* Wih0 = (const float*)d_in[1];
    const float* Whh0 = (const float*)d_in[2];
    const float* bih0 = (const float*)d_in[3];
    const float* bhh0 = (const float*)d_in[4];
    const float* Wih1 = (const float*)d_in[5];
    const float* Whh1 = (const float*)d_in[6];
    const float* bih1 = (const float*)d_in[7];
    const float* bhh1 = (const float*)d_in[8];
    const float* Wfc  = (const float*)d_in[9];
    const float* bfc  = (const float*)d_in[10];
    float* out = (float*)d_out;

    rnn_fused_kernel<<<dim3(BB), dim3(256), 0, stream>>>(
        x, Wih0, Whh0, bih0, bhh0, Wih1, Whh1, bih1, bhh1, Wfc, bfc, out);
}

// Round 3
// 717.061 us; speedup vs baseline: 1.8333x; 1.2459x over previous
//
#include <hip/hip_runtime.h>
#include <hip/hip_bf16.h>

// Fused 2-layer tanh-RNN + FC + sigmoid. One block per batch row.
// Round-3: 8 waves (512 thr, 2 waves/SIMD) x 32 cols/wave so per-wave regs
// fit the 256-unified cap (round-2 spilled 12MB: 1 wave/SIMD needed ~430).
// whh0 in VGPR, wih1/whh1 in AGPR (asm "a"), wih0 in LDS (2 uses/chunk).
// Recurrences of layer0(chunk c) and layer1(chunk c-1) interleaved, one
// barrier per step; xp / u projections batched M=16 per chunk.

#define BB  256
#define SS  512
#define DIN 64
#define HH  256
#define TT  16
#define NC  (SS/TT)

typedef __attribute__((ext_vector_type(8))) short short8;
typedef __attribute__((ext_vector_type(4))) float f32x4;

#define MFMA(a, b, c) __builtin_amdgcn_mfma_f32_16x16x32_bf16((a), (b), (c), 0, 0, 0)

// MFMA with the loop-invariant B operand pinned to the AGPR half of the
// unified register file.
__device__ __forceinline__ void mfma_agpr(f32x4& acc, short8 a, short8 b) {
    asm("v_mfma_f32_16x16x32_bf16 %0, %1, %2, %0" : "+v"(acc) : "v"(a), "a"(b));
}

__device__ __forceinline__ short bf16r(float f) {
    union { float f; unsigned u; } v; v.f = f;
    unsigned r = v.u + 0x7FFFu + ((v.u >> 16) & 1u);   // RTNE
    return (short)(r >> 16);
}

__device__ __forceinline__ float bf2f(ushort h) {
    union { unsigned u; float f; } v; v.u = ((unsigned)h) << 16;
    return v.f;
}

__device__ __forceinline__ short8 ldfrag(const float* __restrict__ p) {
    f32x4 a = *(const f32x4*)p;
    f32x4 b = *(const f32x4*)(p + 4);
    short8 v;
#pragma unroll
    for (int j = 0; j < 4; ++j) { v[j] = bf16r(a[j]); v[4 + j] = bf16r(b[j]); }
    return v;
}

// tanh(x) = 1 - 2/(exp2(2x/ln2)+1)
__device__ __forceinline__ float tanh_fast(float x) {
    float e = __builtin_amdgcn_exp2f(x * 2.885390081777927f);
    return 1.0f - 2.0f * __builtin_amdgcn_rcpf(e + 1.0f);
}

__global__ __launch_bounds__(512, 2)
void rnn_fused_kernel(const float* __restrict__ x,
                      const float* __restrict__ Wih0, const float* __restrict__ Whh0,
                      const float* __restrict__ bih0, const float* __restrict__ bhh0,
                      const float* __restrict__ Wih1, const float* __restrict__ Whh1,
                      const float* __restrict__ bih1, const float* __restrict__ bhh1,
                      const float* __restrict__ Wfc,  const float* __restrict__ bfc,
                      float* __restrict__ out)
{
    const int b    = blockIdx.x;
    const int tid  = threadIdx.x;
    const int wid  = tid >> 6;       // wave 0..7, owns cols [32*wid, 32*wid+32)
    const int lane = tid & 63;
    const int c15  = lane & 15;
    const int kg   = lane >> 4;
    const int cb0  = 32 * wid + c15; // col of n=0 tile; n=1 adds 16

    __shared__ alignas(16) ushort xchunk[TT][DIN];     //  2 KB
    __shared__ alignas(16) float  xp[TT][HH];          // 16 KB  xp + bias0
    __shared__ alignas(16) float  uch[TT][HH];         // 16 KB  u + bias1
    __shared__ alignas(16) ushort h0hist[TT + 1][HH];  // 8.5 KB (slot 0 = carry)
    __shared__ alignas(16) ushort h1pp[2][HH];         //  1 KB  ping-pong
    __shared__ alignas(16) short8 wih0lds[2][16][64];  // 32 KB  staged Wih0 frags

    if (tid < HH) { h0hist[0][tid] = 0; h1pp[1][tid] = 0; }

    // ---- weight fragments (B-frag: col = cb0+16n, k = 32kf + 8kg + j) ----
    float  bias0[2], bias1[2];
    short8 whh0v[8][2];               // VGPR
    short8 wih1a[8][2], whh1a[8][2];  // AGPR via mfma_agpr
#pragma unroll
    for (int n = 0; n < 2; ++n) {
        const int col = cb0 + 16 * n;
        bias0[n] = bih0[col] + bhh0[col];
        bias1[n] = bih1[col] + bhh1[col];
#pragma unroll
        for (int kf = 0; kf < 2; ++kf)
            wih0lds[kf][2 * wid + n][lane] = ldfrag(Wih0 + (size_t)col * DIN + 32 * kf + 8 * kg);
#pragma unroll
        for (int kf = 0; kf < 8; ++kf) {
            whh0v[kf][n] = ldfrag(Whh0 + (size_t)col * HH + 32 * kf + 8 * kg);
            wih1a[kf][n] = ldfrag(Wih1 + (size_t)col * HH + 32 * kf + 8 * kg);
            whh1a[kf][n] = ldfrag(Whh1 + (size_t)col * HH + 32 * kf + 8 * kg);
        }
    }

    const f32x4 vz = {0.f, 0.f, 0.f, 0.f};
    const float* xb = x + (size_t)b * SS * DIN;
    float xr0 = xb[tid], xr1 = xb[tid + 512];
    __syncthreads();   // wih0lds + zero-init visible

    for (int c = 0; c < NC; ++c) {
        // ---- phase A: stage x chunk, xp = x @ Wih0^T + bias0 (M=16) ----
        xchunk[tid >> 6][tid & 63]           = (ushort)bf16r(xr0);
        xchunk[(tid + 512) >> 6][tid & 63]   = (ushort)bf16r(xr1);
        if (c + 1 < NC) {
            const float* xs = xb + (size_t)(c + 1) * TT * DIN;
            xr0 = xs[tid]; xr1 = xs[tid + 512];
        }
        __syncthreads();
        {
            f32x4 axp[2] = {vz, vz};
#pragma unroll
            for (int kf = 0; kf < 2; ++kf) {
                const short8 ax = *(const short8*)(&xchunk[c15][32 * kf + 8 * kg]);
#pragma unroll
                for (int n = 0; n < 2; ++n)
                    axp[n] = MFMA(ax, wih0lds[kf][2 * wid + n][lane], axp[n]);
            }
#pragma unroll
            for (int n = 0; n < 2; ++n)
#pragma unroll
                for (int j = 0; j < 4; ++j)
                    xp[4 * kg + j][cb0 + 16 * n] = axp[n][j] + bias0[n];
        }
        __syncthreads();

        // ---- phase B(c) interleaved with D(c-1): the two recurrences ----
        const bool doD = (c > 0);
        for (int r = 0; r < TT; ++r) {
            const int dcur = r & 1, dprv = dcur ^ 1;
            float xpv[2], uv[2] = {0.f, 0.f};
#pragma unroll
            for (int n = 0; n < 2; ++n) xpv[n] = xp[r][cb0 + 16 * n];
            if (doD) {
#pragma unroll
                for (int n = 0; n < 2; ++n) uv[n] = uch[r][cb0 + 16 * n];
            }
            f32x4 a0[2] = {vz, vz}, a1[2] = {vz, vz};
#pragma unroll
            for (int kf = 0; kf < 8; ++kf) {
                const short8 ah0 = *(const short8*)(&h0hist[r][32 * kf + 8 * kg]);
                a0[0] = MFMA(ah0, whh0v[kf][0], a0[0]);
                a0[1] = MFMA(ah0, whh0v[kf][1], a0[1]);
                if (doD) {
                    const short8 ah1 = *(const short8*)(&h1pp[dprv][32 * kf + 8 * kg]);
                    mfma_agpr(a1[0], ah1, whh1a[kf][0]);
                    mfma_agpr(a1[1], ah1, whh1a[kf][1]);
                }
            }
            if (lane < 16) {
#pragma unroll
                for (int n = 0; n < 2; ++n)
                    h0hist[r + 1][32 * wid + 16 * n + lane] =
                        (ushort)bf16r(tanh_fast(a0[n][0] + xpv[n]));
                if (doD) {
#pragma unroll
                    for (int n = 0; n < 2; ++n)
                        h1pp[dcur][32 * wid + 16 * n + lane] =
                            (ushort)bf16r(tanh_fast(a1[n][0] + uv[n]));
                }
            }
            __syncthreads();
        }

        // ---- phase C: u(c) = h0 @ Wih1^T + bias1 (M=16 rows = timesteps) ----
        {
            f32x4 au[2] = {vz, vz};
#pragma unroll
            for (int kf = 0; kf < 8; ++kf) {
                const short8 a = *(const short8*)(&h0hist[1 + c15][32 * kf + 8 * kg]);
                mfma_agpr(au[0], a, wih1a[kf][0]);
                mfma_agpr(au[1], a, wih1a[kf][1]);
            }
#pragma unroll
            for (int n = 0; n < 2; ++n)
#pragma unroll
                for (int j = 0; j < 4; ++j)
                    uch[4 * kg + j][cb0 + 16 * n] = au[n][j] + bias1[n];
            if (tid < HH) h0hist[0][tid] = h0hist[TT][tid];   // carry
        }
        __syncthreads();
    }

    // ---- drain: layer-1 recurrence for the last chunk ----
    for (int r = 0; r < TT; ++r) {
        const int dcur = r & 1, dprv = dcur ^ 1;
        float uv[2];
#pragma unroll
        for (int n = 0; n < 2; ++n) uv[n] = uch[r][cb0 + 16 * n];
        f32x4 a1[2] = {vz, vz};
#pragma unroll
        for (int kf = 0; kf < 8; ++kf) {
            const short8 ah1 = *(const short8*)(&h1pp[dprv][32 * kf + 8 * kg]);
            mfma_agpr(a1[0], ah1, whh1a[kf][0]);
            mfma_agpr(a1[1], ah1, whh1a[kf][1]);
        }
        if (lane < 16) {
#pragma unroll
            for (int n = 0; n < 2; ++n)
                h1pp[dcur][32 * wid + 16 * n + lane] =
                    (ushort)bf16r(tanh_fast(a1[n][0] + uv[n]));
        }
        __syncthreads();
    }

    // ---- FC + sigmoid on final h1 (last step r=15 -> parity 1) ----
    if (wid == 0) {
        float p = 0.f;
#pragma unroll
        for (int i = 0; i < 4; ++i)
            p += bf2f(h1pp[1][4 * lane + i]) * Wfc[4 * lane + i];
#pragma unroll
        for (int off = 32; off > 0; off >>= 1) p += __shfl_down(p, off);
        if (lane == 0) {
            const float z = p + bfc[0];
            out[b] = 1.f / (1.f + expf(-z));
        }
    }
}

extern "C" void kernel_launch(void* const* d_in, const int* in_sizes, int n_in,
                              void* d_out, int out_size, void* d_ws, size_t ws_size,
                              hipStream_t stream) {
    (void)in_sizes; (void)n_in; (void)d_ws; (void)ws_size; (void)out_size;
    const float* x    = (const float*)d_in[0];
    const float* Wih0 = (const float*)d_in[1];
    const float* Whh0 = (const float*)d_in[2];
    const float* bih0 = (const float*)d_in[3];
    const float* bhh0 = (const float*)d_in[4];
    const float* Wih1 = (const float*)d_in[5];
    const float* Whh1 = (const float*)d_in[6];
    const float* bih1 = (const float*)d_in[7];
    const float* bhh1 = (const float*)d_in[8];
    const float* Wfc  = (const float*)d_in[9];
    const float* bfc  = (const float*)d_in[10];
    float* out = (float*)d_out;

    rnn_fused_kernel<<<dim3(BB), dim3(512), 0, stream>>>(
        x, Wih0, Whh0, bih0, bhh0, Wih1, Whh1, bih1, bhh1, Wfc, bfc, out);
}

// Round 4
// 692.569 us; speedup vs baseline: 1.8982x; 1.0354x over previous
//
#include <hip/hip_runtime.h>
#include <hip/hip_bf16.h>

// Fused 2-layer tanh-RNN + FC + sigmoid. One block per batch row, 8 waves
// (512 thr, 2 waves/SIMD), wave owns 32 output cols.
// Round-4: ALL three HxH weight sets (Whh0, Wih1, Whh1) are AGPR-pinned via
// inline-asm MFMA "a" operands (192 AGPR/wave). Round-3 kept Whh0 as a
// builtin-MFMA "v" operand; with only 64 free VGPRs the allocator shuttled
// it through AGPRs with v_accvgpr_read every step (VALUBusy 50% > MfmaUtil
// 35%). Accumulator zero-init passes a hoisted zero register as the asm C
// operand for kf=0 (no per-step v_mov trains).

#define BB  256
#define SS  512
#define DIN 64
#define HH  256
#define TT  16
#define NC  (SS/TT)

typedef __attribute__((ext_vector_type(8))) short short8;
typedef __attribute__((ext_vector_type(4))) float f32x4;

#define MFMA(a, b, c) __builtin_amdgcn_mfma_f32_16x16x32_bf16((a), (b), (c), 0, 0, 0)

// acc += A * B with B pinned in AGPRs
__device__ __forceinline__ void mfma_a(f32x4& acc, short8 a, short8 b) {
    asm("v_mfma_f32_16x16x32_bf16 %0, %1, %2, %0" : "+v"(acc) : "v"(a), "a"(b));
}
// acc = A * B + C (C = hoisted zero register; no per-step init movs)
__device__ __forceinline__ f32x4 mfma_az(short8 a, short8 b, f32x4 c) {
    f32x4 d;
    asm("v_mfma_f32_16x16x32_bf16 %0, %1, %2, %3"
        : "=&v"(d) : "v"(a), "a"(b), "v"(c));
    return d;
}

__device__ __forceinline__ short bf16r(float f) {
    union { float f; unsigned u; } v; v.f = f;
    unsigned r = v.u + 0x7FFFu + ((v.u >> 16) & 1u);   // RTNE
    return (short)(r >> 16);
}

__device__ __forceinline__ float bf2f(ushort h) {
    union { unsigned u; float f; } v; v.u = ((unsigned)h) << 16;
    return v.f;
}

__device__ __forceinline__ short8 ldfrag(const float* __restrict__ p) {
    f32x4 a = *(const f32x4*)p;
    f32x4 b = *(const f32x4*)(p + 4);
    short8 v;
#pragma unroll
    for (int j = 0; j < 4; ++j) { v[j] = bf16r(a[j]); v[4 + j] = bf16r(b[j]); }
    return v;
}

// tanh(x) = 1 - 2/(exp2(2x/ln2)+1)
__device__ __forceinline__ float tanh_fast(float x) {
    float e = __builtin_amdgcn_exp2f(x * 2.885390081777927f);
    return 1.0f - 2.0f * __builtin_amdgcn_rcpf(e + 1.0f);
}

__global__ __launch_bounds__(512, 2)
void rnn_fused_kernel(const float* __restrict__ x,
                      const float* __restrict__ Wih0, const float* __restrict__ Whh0,
                      const float* __restrict__ bih0, const float* __restrict__ bhh0,
                      const float* __restrict__ Wih1, const float* __restrict__ Whh1,
                      const float* __restrict__ bih1, const float* __restrict__ bhh1,
                      const float* __restrict__ Wfc,  const float* __restrict__ bfc,
                      float* __restrict__ out)
{
    const int b    = blockIdx.x;
    const int tid  = threadIdx.x;
    const int wid  = tid >> 6;       // wave 0..7, owns cols [32*wid, 32*wid+32)
    const int lane = tid & 63;
    const int c15  = lane & 15;
    const int kg   = lane >> 4;
    const int cb0  = 32 * wid + c15; // col of n=0 tile; n=1 adds 16

    __shared__ alignas(16) ushort xchunk[TT][DIN];     //  2 KB
    __shared__ alignas(16) float  xp[TT][HH];          // 16 KB  xp + bias0
    __shared__ alignas(16) float  uch[TT][HH];         // 16 KB  u + bias1
    __shared__ alignas(16) ushort h0hist[TT + 1][HH];  // 8.5 KB (slot 0 = carry)
    __shared__ alignas(16) ushort h1pp[2][HH];         //  1 KB  ping-pong
    __shared__ alignas(16) short8 wih0lds[2][16][64];  // 32 KB  staged Wih0 frags

    if (tid < HH) { h0hist[0][tid] = 0; h1pp[1][tid] = 0; }

    // ---- weight fragments (B-frag: col = cb0+16n, k = 32kf + 8kg + j) ----
    float  bias0[2], bias1[2];
    short8 whh0a[8][2], wih1a[8][2], whh1a[8][2];   // all AGPR via asm "a"
#pragma unroll
    for (int n = 0; n < 2; ++n) {
        const int col = cb0 + 16 * n;
        bias0[n] = bih0[col] + bhh0[col];
        bias1[n] = bih1[col] + bhh1[col];
#pragma unroll
        for (int kf = 0; kf < 2; ++kf)
            wih0lds[kf][2 * wid + n][lane] = ldfrag(Wih0 + (size_t)col * DIN + 32 * kf + 8 * kg);
#pragma unroll
        for (int kf = 0; kf < 8; ++kf) {
            whh0a[kf][n] = ldfrag(Whh0 + (size_t)col * HH + 32 * kf + 8 * kg);
            wih1a[kf][n] = ldfrag(Wih1 + (size_t)col * HH + 32 * kf + 8 * kg);
            whh1a[kf][n] = ldfrag(Whh1 + (size_t)col * HH + 32 * kf + 8 * kg);
        }
    }

    const f32x4 vz = {0.f, 0.f, 0.f, 0.f};
    const float* xb = x + (size_t)b * SS * DIN;
    float xr0 = xb[tid], xr1 = xb[tid + 512];
    __syncthreads();   // wih0lds + zero-init visible

    for (int c = 0; c < NC; ++c) {
        // ---- phase A: stage x chunk, xp = x @ Wih0^T + bias0 (M=16) ----
        xchunk[tid >> 6][tid & 63]         = (ushort)bf16r(xr0);
        xchunk[(tid + 512) >> 6][tid & 63] = (ushort)bf16r(xr1);
        if (c + 1 < NC) {
            const float* xs = xb + (size_t)(c + 1) * TT * DIN;
            xr0 = xs[tid]; xr1 = xs[tid + 512];
        }
        __syncthreads();
        {
            f32x4 axp[2] = {vz, vz};
#pragma unroll
            for (int kf = 0; kf < 2; ++kf) {
                const short8 ax = *(const short8*)(&xchunk[c15][32 * kf + 8 * kg]);
#pragma unroll
                for (int n = 0; n < 2; ++n)
                    axp[n] = MFMA(ax, wih0lds[kf][2 * wid + n][lane], axp[n]);
            }
#pragma unroll
            for (int n = 0; n < 2; ++n)
#pragma unroll
                for (int j = 0; j < 4; ++j)
                    xp[4 * kg + j][cb0 + 16 * n] = axp[n][j] + bias0[n];
        }
        __syncthreads();

        // ---- phase B(c) interleaved with D(c-1): the two recurrences ----
        const bool doD = (c > 0);
        for (int r = 0; r < TT; ++r) {
            const int dcur = r & 1, dprv = dcur ^ 1;
            float xpv[2], uv[2] = {0.f, 0.f};
#pragma unroll
            for (int n = 0; n < 2; ++n) xpv[n] = xp[r][cb0 + 16 * n];
            if (doD) {
#pragma unroll
                for (int n = 0; n < 2; ++n) uv[n] = uch[r][cb0 + 16 * n];
            }
            f32x4 a0[2], a1[2];
            {   // kf = 0: C = hoisted zero reg
                const short8 ah0 = *(const short8*)(&h0hist[r][8 * kg]);
                a0[0] = mfma_az(ah0, whh0a[0][0], vz);
                a0[1] = mfma_az(ah0, whh0a[0][1], vz);
                if (doD) {
                    const short8 ah1 = *(const short8*)(&h1pp[dprv][8 * kg]);
                    a1[0] = mfma_az(ah1, whh1a[0][0], vz);
                    a1[1] = mfma_az(ah1, whh1a[0][1], vz);
                }
            }
#pragma unroll
            for (int kf = 1; kf < 8; ++kf) {
                const short8 ah0 = *(const short8*)(&h0hist[r][32 * kf + 8 * kg]);
                mfma_a(a0[0], ah0, whh0a[kf][0]);
                mfma_a(a0[1], ah0, whh0a[kf][1]);
                if (doD) {
                    const short8 ah1 = *(const short8*)(&h1pp[dprv][32 * kf + 8 * kg]);
                    mfma_a(a1[0], ah1, whh1a[kf][0]);
                    mfma_a(a1[1], ah1, whh1a[kf][1]);
                }
            }
            if (lane < 16) {
#pragma unroll
                for (int n = 0; n < 2; ++n)
                    h0hist[r + 1][32 * wid + 16 * n + lane] =
                        (ushort)bf16r(tanh_fast(a0[n][0] + xpv[n]));
                if (doD) {
#pragma unroll
                    for (int n = 0; n < 2; ++n)
                        h1pp[dcur][32 * wid + 16 * n + lane] =
                            (ushort)bf16r(tanh_fast(a1[n][0] + uv[n]));
                }
            }
            __syncthreads();
        }

        // ---- phase C: u(c) = h0 @ Wih1^T + bias1 (M=16 rows = timesteps) ----
        {
            f32x4 au[2];
            {
                const short8 a = *(const short8*)(&h0hist[1 + c15][8 * kg]);
                au[0] = mfma_az(a, wih1a[0][0], vz);
                au[1] = mfma_az(a, wih1a[0][1], vz);
            }
#pragma unroll
            for (int kf = 1; kf < 8; ++kf) {
                const short8 a = *(const short8*)(&h0hist[1 + c15][32 * kf + 8 * kg]);
                mfma_a(au[0], a, wih1a[kf][0]);
                mfma_a(au[1], a, wih1a[kf][1]);
            }
#pragma unroll
            for (int n = 0; n < 2; ++n)
#pragma unroll
                for (int j = 0; j < 4; ++j)
                    uch[4 * kg + j][cb0 + 16 * n] = au[n][j] + bias1[n];
            if (tid < HH) h0hist[0][tid] = h0hist[TT][tid];   // carry
        }
        __syncthreads();
    }

    // ---- drain: layer-1 recurrence for the last chunk ----
    for (int r = 0; r < TT; ++r) {
        const int dcur = r & 1, dprv = dcur ^ 1;
        float uv[2];
#pragma unroll
        for (int n = 0; n < 2; ++n) uv[n] = uch[r][cb0 + 16 * n];
        f32x4 a1[2];
        {
            const short8 ah1 = *(const short8*)(&h1pp[dprv][8 * kg]);
            a1[0] = mfma_az(ah1, whh1a[0][0], vz);
            a1[1] = mfma_az(ah1, whh1a[0][1], vz);
        }
#pragma unroll
        for (int kf = 1; kf < 8; ++kf) {
            const short8 ah1 = *(const short8*)(&h1pp[dprv][32 * kf + 8 * kg]);
            mfma_a(a1[0], ah1, whh1a[kf][0]);
            mfma_a(a1[1], ah1, whh1a[kf][1]);
        }
        if (lane < 16) {
#pragma unroll
            for (int n = 0; n < 2; ++n)
                h1pp[dcur][32 * wid + 16 * n + lane] =
                    (ushort)bf16r(tanh_fast(a1[n][0] + uv[n]));
        }
        __syncthreads();
    }

    // ---- FC + sigmoid on final h1 (last step r=15 -> parity 1) ----
    if (wid == 0) {
        float p = 0.f;
#pragma unroll
        for (int i = 0; i < 4; ++i)
            p += bf2f(h1pp[1][4 * lane + i]) * Wfc[4 * lane + i];
#pragma unroll
        for (int off = 32; off > 0; off >>= 1) p += __shfl_down(p, off);
        if (lane == 0) {
            const float z = p + bfc[0];
            out[b] = 1.f / (1.f + expf(-z));
        }
    }
}

extern "C" void kernel_launch(void* const* d_in, const int* in_sizes, int n_in,
                              void* d_out, int out_size, void* d_ws, size_t ws_size,
                              hipStream_t stream) {
    (void)in_sizes; (void)n_in; (void)d_ws; (void)ws_size; (void)out_size;
    const float* x    = (const float*)d_in[0];
    const float* Wih0 = (const float*)d_in[1];
    const float* Whh0 = (const float*)d_in[2];
    const float* bih0 = (const float*)d_in[3];
    const float* bhh0 = (const float*)d_in[4];
    const float* Wih1 = (const float*)d_in[5];
    const float* Whh1 = (const float*)d_in[6];
    const float* bih1 = (const float*)d_in[7];
    const float* bhh1 = (const float*)d_in[8];
    const float* Wfc  = (const float*)d_in[9];
    const float* bfc  = (const float*)d_in[10];
    float* out = (float*)d_out;

    rnn_fused_kernel<<<dim3(BB), dim3(512), 0, stream>>>(
        x, Wih0, Whh0, bih0, bhh0, Wih1, Whh1, bih1, bhh1, Wfc, bfc, out);
}